// Round 2
// baseline (985.898 us; speedup 1.0000x reference)
//
#include <hip/hip_runtime.h>

#define T_ 16
#define B_ 128
#define S_ 10
#define FP_ 64
#define DP_ 28
#define CP_ 37
#define NPOS (CP_*CP_)     // 1369
#define KPAD 1376          // 43*32, zero-padded tail
#define H_ 256
#define O_ (S_*B_)         // 1280 output channels
#define M_TOT (T_*O_)      // 20480 rows
#define NOUT 40960         // S*B*T*2

typedef _Float16 half8 __attribute__((ext_vector_type(8)));

// ---------------- threefry2x32 (JAX key(1) => (0,1)) + XLA-style normal ----
#define TF_ROT(x, r) (((x) << (r)) | ((x) >> (32 - (r))))
#define TF_ROUND(r) { x0 += x1; x1 = TF_ROT(x1, (r)); x1 ^= x0; }

__device__ __forceinline__ float erfinv_f(float x) {
  float w = -log1pf(-x * x);
  float p;
  if (w < 5.0f) {
    w -= 2.5f;
    p = 2.81022636e-08f;
    p = fmaf(p, w, 3.43273939e-07f);
    p = fmaf(p, w, -3.5233877e-06f);
    p = fmaf(p, w, -4.39150654e-06f);
    p = fmaf(p, w, 0.00021858087f);
    p = fmaf(p, w, -0.00125372503f);
    p = fmaf(p, w, -0.00417768164f);
    p = fmaf(p, w, 0.246640727f);
    p = fmaf(p, w, 1.50140941f);
  } else {
    w = sqrtf(w) - 3.0f;
    p = -0.000200214257f;
    p = fmaf(p, w, 0.000100950558f);
    p = fmaf(p, w, 0.00134934322f);
    p = fmaf(p, w, -0.00367342844f);
    p = fmaf(p, w, 0.00573950773f);
    p = fmaf(p, w, -0.0076224613f);
    p = fmaf(p, w, 0.00943887047f);
    p = fmaf(p, w, 1.00167406f);
    p = fmaf(p, w, 2.83297682f);
  }
  return p * x;
}

// eps[p] for flat index p in the (S,B,T,2) normal sample, matching
// jax.random.normal(jax.random.key(1), (S,B,T,2), float32) with
// jax_threefry_partitionable=True (default in recent JAX):
//   per-element counter (hi=0, lo=p), bits = out0 ^ out1.
__device__ __forceinline__ float gauss_eps(int p) {
  const unsigned ks0 = 0u, ks1 = 1u, ks2 = 0x1BD11BDBu; // 0^1^0x1BD11BDA
  unsigned x0 = 0u + ks0;            // counts_hi = 0
  unsigned x1 = (unsigned)p + ks1;   // counts_lo = p
  TF_ROUND(13) TF_ROUND(15) TF_ROUND(26) TF_ROUND(6)
  x0 += ks1; x1 += ks2 + 1u;
  TF_ROUND(17) TF_ROUND(29) TF_ROUND(16) TF_ROUND(24)
  x0 += ks2; x1 += ks0 + 2u;
  TF_ROUND(13) TF_ROUND(15) TF_ROUND(26) TF_ROUND(6)
  x0 += ks0; x1 += ks1 + 3u;
  TF_ROUND(17) TF_ROUND(29) TF_ROUND(16) TF_ROUND(24)
  x0 += ks1; x1 += ks2 + 4u;
  TF_ROUND(13) TF_ROUND(15) TF_ROUND(26) TF_ROUND(6)
  x0 += ks2; x1 += ks0 + 5u;
  unsigned bits = x0 ^ x1;
  unsigned fb = (bits >> 9) | 0x3f800000u;
  float f = __uint_as_float(fb) - 1.0f;          // [0,1)
  const float lo = -0.99999994f;                 // nextafter(-1,0)
  float u = f * 2.0f + lo;                       // (hi-lo) rounds to exactly 2.0f
  u = fmaxf(lo, u);
  float r = erfinv_f(u);
  return 1.41421356f * r;                        // sqrt(2) (f32)
}

// ---------------- stage 1: grouped correlation ----------------------------
// block = (g, t): g = frame channel 0..127, t = 0..15.
// conv_out[(t*1280 + 10g + s)*KPAD + (y*37+x)] =
//   sum_{i,j} frames[g,t,y+i,x+j] * digits[(10g+s)*784 + i*28 + j]
__global__ __launch_bounds__(256) void conv_kernel(
    const float* __restrict__ frames, const float* __restrict__ digits,
    _Float16* __restrict__ conv_out)
{
  __shared__ float fr[FP_*FP_];      // 16 KB
  __shared__ float dg[S_*DP_*DP_];   // 31.4 KB
  const int g = blockIdx.x >> 4;
  const int t = blockIdx.x & 15;
  const int tid = threadIdx.x;

  {
    const float4* fsrc = (const float4*)(frames + ((size_t)g*T_ + t)*(FP_*FP_));
    float4* fdst = (float4*)fr;
    #pragma unroll
    for (int k = 0; k < 4; ++k) fdst[tid + 256*k] = fsrc[tid + 256*k];
    const float4* dsrc = (const float4*)(digits + (size_t)g*(S_*DP_*DP_));
    float4* ddst = (float4*)dg;
    #pragma unroll
    for (int k = 0; k < 8; ++k) {
      int idx = tid + 256*k;
      if (idx < (S_*DP_*DP_)/4) ddst[idx] = dsrc[idx];
    }
  }
  __syncthreads();

  int py[6], px[6]; bool vld[6];
  #pragma unroll
  for (int sl = 0; sl < 6; ++sl) {
    int p = tid + 256*sl;
    vld[sl] = (p < NPOS);
    int pc = vld[sl] ? p : 0;
    py[sl] = pc / CP_; px[sl] = pc - CP_*py[sl];
  }

  float acc[6][S_];
  #pragma unroll
  for (int sl = 0; sl < 6; ++sl)
    #pragma unroll
    for (int s = 0; s < S_; ++s) acc[sl][s] = 0.f;

  for (int i = 0; i < DP_; ++i) {
    const float* dgi = dg + i*DP_;
    for (int j = 0; j < DP_; j += 2) {
      float2 d[S_];
      #pragma unroll
      for (int s = 0; s < S_; ++s)
        d[s] = *(const float2*)&dgi[s*(DP_*DP_) + j];   // 8B-aligned
      #pragma unroll
      for (int sl = 0; sl < 6; ++sl) {
        const float* frow = fr + (py[sl]+i)*FP_ + px[sl] + j;
        float f0 = frow[0], f1 = frow[1];
        #pragma unroll
        for (int s = 0; s < S_; ++s) {
          acc[sl][s] = fmaf(f0, d[s].x, acc[sl][s]);
          acc[sl][s] = fmaf(f1, d[s].y, acc[sl][s]);
        }
      }
    }
  }

  #pragma unroll
  for (int sl = 0; sl < 6; ++sl) {
    if (!vld[sl]) continue;
    int p = tid + 256*sl;
    #pragma unroll
    for (int s = 0; s < S_; ++s) {
      size_t row = (size_t)t*O_ + 10*g + s;
      conv_out[row*KPAD + p] = (_Float16)acc[sl][s];
    }
  }
  // zero the K padding (cols 1369..1375) for this block's 10 rows
  if (tid < 70) {
    int s = tid / 7, pp = NPOS + (tid % 7);
    size_t row = (size_t)t*O_ + 10*g + s;
    conv_out[row*KPAD + pp] = (_Float16)0.f;
  }
}

// ---------------- stage 2+3: hidden=tanh(conv@W1+b1); q=tanh(hidden@W2+b2);
//                  z = q + std*eps; fused epilogue ------------------------
__global__ __launch_bounds__(256) void mlp_kernel(
    const _Float16* __restrict__ conv_out,
    const float* __restrict__ W1, const float* __restrict__ b1,
    const float* __restrict__ W2, const float* __restrict__ b2,
    const float* __restrict__ wstd,
    float* __restrict__ out)
{
  __shared__ float aT[32][72];    // [kk][m] transposed A tile, 9.2 KB
  __shared__ float wT[32][260];   // [kk][h] W1 tile, 33.3 KB
  const int tid = threadIdx.x;
  const int m0 = blockIdx.x * 64;
  const int mg = tid >> 5;        // 0..7 -> rows m0+mg*8 .. +7
  const int hl = tid & 31;
  const int h0 = hl * 8;          // 8 h-columns per thread

  float acc[8][8];
  #pragma unroll
  for (int e = 0; e < 8; ++e)
    #pragma unroll
    for (int f = 0; f < 8; ++f) acc[e][f] = 0.f;

  for (int k0 = 0; k0 < KPAD; k0 += 32) {
    __syncthreads();
    { // stage A: 64 m x 32 k (f16 -> f32, transposed)
      int m = m0 + (tid >> 2);
      int kk0 = (tid & 3) * 8;
      half8 v = *(const half8*)(conv_out + (size_t)m*KPAD + k0 + kk0);
      #pragma unroll
      for (int e = 0; e < 8; ++e) aT[kk0+e][tid>>2] = (float)v[e];
    }
    { // stage W1: 32 k x 256 h
      int kk = tid >> 3;
      int k = k0 + kk;
      int cb = (tid & 7) * 4;
      #pragma unroll
      for (int r = 0; r < 8; ++r) {
        int c = cb + r*32;
        float4 v = make_float4(0.f,0.f,0.f,0.f);
        if (k < NPOS) v = *(const float4*)(W1 + (size_t)k*H_ + c);
        *(float4*)&wT[kk][c] = v;
      }
    }
    __syncthreads();
    #pragma unroll 4
    for (int kk = 0; kk < 32; ++kk) {
      float4 a0 = *(const float4*)&aT[kk][mg*8];
      float4 a1 = *(const float4*)&aT[kk][mg*8+4];
      float4 w0 = *(const float4*)&wT[kk][h0];
      float4 w1 = *(const float4*)&wT[kk][h0+4];
      float a[8] = {a0.x,a0.y,a0.z,a0.w,a1.x,a1.y,a1.z,a1.w};
      float w[8] = {w0.x,w0.y,w0.z,w0.w,w1.x,w1.y,w1.z,w1.w};
      #pragma unroll
      for (int e = 0; e < 8; ++e)
        #pragma unroll
        for (int f = 0; f < 8; ++f)
          acc[e][f] = fmaf(a[e], w[f], acc[e][f]);
    }
  }

  // epilogue: tanh + tiny second GEMM (partial over this thread's 8 h)
  float qp[8][2];
  #pragma unroll
  for (int e = 0; e < 8; ++e) { qp[e][0] = 0.f; qp[e][1] = 0.f; }
  #pragma unroll
  for (int f = 0; f < 8; ++f) {
    float bb = b1[h0+f];
    float w20 = W2[(h0+f)*2 + 0];
    float w21 = W2[(h0+f)*2 + 1];
    #pragma unroll
    for (int e = 0; e < 8; ++e) {
      float h = tanhf(acc[e][f] + bb);
      qp[e][0] = fmaf(h, w20, qp[e][0]);
      qp[e][1] = fmaf(h, w21, qp[e][1]);
    }
  }
  // reduce across the 32 lanes sharing this m-group (stay within 32-halves)
  #pragma unroll
  for (int off = 16; off >= 1; off >>= 1) {
    #pragma unroll
    for (int e = 0; e < 8; ++e) {
      qp[e][0] += __shfl_xor(qp[e][0], off);
      qp[e][1] += __shfl_xor(qp[e][1], off);
    }
  }

  if (hl == 0) {
    float s0 = wstd[0], s1 = wstd[1];
    float bb0 = b2[0], bb1 = b2[1];
    #pragma unroll
    for (int e = 0; e < 8; ++e) {
      int m = m0 + mg*8 + e;            // m = t*1280 + o,  o = s*B+b
      int t = m / O_;
      int o = m - t*O_;
      int base = (o*T_ + t)*2;          // q_mean flat index, c=0
      float q0 = tanhf(qp[e][0] + bb0);
      float q1 = tanhf(qp[e][1] + bb1);
      out[base]   = q0;
      out[base+1] = q1;
      out[NOUT + base]   = q0 + s0 * gauss_eps(base);
      out[NOUT + base+1] = q1 + s1 * gauss_eps(base+1);
    }
  }
}

extern "C" void kernel_launch(void* const* d_in, const int* in_sizes, int n_in,
                              void* d_out, int out_size, void* d_ws, size_t ws_size,
                              hipStream_t stream) {
  const float* frames = (const float*)d_in[0];
  const float* digits = (const float*)d_in[1];
  // d_in[2] is S (=10), unused
  const float* W1   = (const float*)d_in[3];
  const float* b1   = (const float*)d_in[4];
  const float* W2   = (const float*)d_in[5];
  const float* b2   = (const float*)d_in[6];
  const float* wstd = (const float*)d_in[7];
  _Float16* conv_out = (_Float16*)d_ws;      // [20480][1376] f16 = 56.4 MB
  float* out = (float*)d_out;

  conv_kernel<<<dim3(B_*T_), dim3(256), 0, stream>>>(frames, digits, conv_out);
  mlp_kernel<<<dim3(M_TOT/64), dim3(256), 0, stream>>>(conv_out, W1, b1, W2, b2, wstd, out);
}

// Round 3
// 271.835 us; speedup vs baseline: 3.6268x; 3.6268x over previous
//
#include <hip/hip_runtime.h>
#include <stdint.h>

#define CROWB 2816        // conv_out row bytes (1408 f16, K padded 1369->1408)
#define NOUT 40960

typedef _Float16 f16x8 __attribute__((ext_vector_type(8)));
typedef float f32x4 __attribute__((ext_vector_type(4)));

// ---------------- threefry2x32 (key(1) -> (0,1)), partitionable path ------
#define TF_ROT(x, r) (((x) << (r)) | ((x) >> (32 - (r))))
#define TF_ROUND(r) { x0 += x1; x1 = TF_ROT(x1, (r)); x1 ^= x0; }

__device__ __forceinline__ float erfinv_f(float x) {
  float w = -log1pf(-x * x);
  float p;
  if (w < 5.0f) {
    w -= 2.5f;
    p = 2.81022636e-08f;
    p = fmaf(p, w, 3.43273939e-07f);
    p = fmaf(p, w, -3.5233877e-06f);
    p = fmaf(p, w, -4.39150654e-06f);
    p = fmaf(p, w, 0.00021858087f);
    p = fmaf(p, w, -0.00125372503f);
    p = fmaf(p, w, -0.00417768164f);
    p = fmaf(p, w, 0.246640727f);
    p = fmaf(p, w, 1.50140941f);
  } else {
    w = sqrtf(w) - 3.0f;
    p = -0.000200214257f;
    p = fmaf(p, w, 0.000100950558f);
    p = fmaf(p, w, 0.00134934322f);
    p = fmaf(p, w, -0.00367342844f);
    p = fmaf(p, w, 0.00573950773f);
    p = fmaf(p, w, -0.0076224613f);
    p = fmaf(p, w, 0.00943887047f);
    p = fmaf(p, w, 1.00167406f);
    p = fmaf(p, w, 2.83297682f);
  }
  return p * x;
}

__device__ __forceinline__ float gauss_eps(int p) {
  const unsigned ks0 = 0u, ks1 = 1u, ks2 = 0x1BD11BDBu;
  unsigned x0 = 0u + ks0;
  unsigned x1 = (unsigned)p + ks1;
  TF_ROUND(13) TF_ROUND(15) TF_ROUND(26) TF_ROUND(6)
  x0 += ks1; x1 += ks2 + 1u;
  TF_ROUND(17) TF_ROUND(29) TF_ROUND(16) TF_ROUND(24)
  x0 += ks2; x1 += ks0 + 2u;
  TF_ROUND(13) TF_ROUND(15) TF_ROUND(26) TF_ROUND(6)
  x0 += ks0; x1 += ks1 + 3u;
  TF_ROUND(17) TF_ROUND(29) TF_ROUND(16) TF_ROUND(24)
  x0 += ks1; x1 += ks2 + 4u;
  TF_ROUND(13) TF_ROUND(15) TF_ROUND(26) TF_ROUND(6)
  x0 += ks2; x1 += ks0 + 5u;
  unsigned bits = x0 ^ x1;
  unsigned fb = (bits >> 9) | 0x3f800000u;
  float f = __uint_as_float(fb) - 1.0f;
  const float lo = -0.99999994f;
  float u = f * 2.0f + lo;
  u = fmaxf(lo, u);
  return 1.41421356f * erfinv_f(u);
}

__device__ __forceinline__ float fast_tanh(float x) {
  float e = __expf(2.0f * x);                 // v_exp_f32 based
  return 1.0f - 2.0f * __builtin_amdgcn_rcpf(e + 1.0f);
}

__device__ __forceinline__ uint32_t packh2(float lo, float hi) {
  union { _Float16 h[2]; uint32_t u; } c;
  c.h[0] = (_Float16)lo; c.h[1] = (_Float16)hi;
  return c.u;
}

// ---------------- W1 transpose+f16 prep: w1t[h][k] (k padded to 1408) -----
__global__ void prep_w1t(const float* __restrict__ W1, uint8_t* __restrict__ w1t) {
  int k = blockIdx.x;          // 0..1407
  int h = threadIdx.x;         // 0..255
  float v = (k < 1369) ? W1[(size_t)k * 256 + h] : 0.0f;
  *(_Float16*)(w1t + (size_t)h * CROWB + (size_t)k * 2) = (_Float16)v;
}

// ---------------- stage 1: grouped correlation via MFMA -------------------
// block = (g,t).  C[p][s] = sum_{i,j} F[py+i][px+j] * D[s][i][j]
// A (M=16 pos x K=32) from dual-shifted f16 frame copies; B = digits f16.
__global__ __launch_bounds__(256, 3) void conv_mfma(
    const float* __restrict__ frames, const float* __restrict__ digits,
    uint8_t* __restrict__ conv_out)
{
  // [0,8192) copyE f16[4096]; [8192,16384) copyO (elems shifted by 1);
  // [16384, 16384+28928) dgh f16[16][904]  (904 = 28*32 + 8 pad)
  __shared__ __align__(16) uint8_t smem[45312];
  const int g = blockIdx.x >> 4, t = blockIdx.x & 15;
  const int tid = threadIdx.x;
  const int lane = tid & 63, w = tid >> 6;
  const int l15 = lane & 15, lg = lane >> 4;
  const int jo = lg * 8;

  // ---- stage frames -> copyE/copyO (f32 -> f16 RNE) ----
  {
    const float* fbase = frames + ((size_t)(g * 16 + t)) * 4096;
    float f[16];
    const float4* f4 = (const float4*)(fbase + tid * 16);
    #pragma unroll
    for (int a = 0; a < 4; ++a) {
      float4 v = f4[a];
      f[4*a] = v.x; f[4*a+1] = v.y; f[4*a+2] = v.z; f[4*a+3] = v.w;
    }
    float nxt = __shfl_down(f[0], 1);
    if ((tid & 63) == 63) nxt = (tid == 255) ? 0.0f : fbase[tid * 16 + 16];
    uint32_t we[8], wo[8];
    #pragma unroll
    for (int a = 0; a < 8; ++a) {
      we[a] = packh2(f[2*a], f[2*a+1]);
      float hi = (a == 7) ? nxt : f[2*a+2];
      wo[a] = packh2(f[2*a+1], hi);
    }
    *(uint4*)(smem + tid * 32)          = make_uint4(we[0], we[1], we[2], we[3]);
    *(uint4*)(smem + tid * 32 + 16)     = make_uint4(we[4], we[5], we[6], we[7]);
    *(uint4*)(smem + 8192 + tid * 32)   = make_uint4(wo[0], wo[1], wo[2], wo[3]);
    *(uint4*)(smem + 8192 + tid * 32 + 16) = make_uint4(wo[4], wo[5], wo[6], wo[7]);
  }
  // ---- zero dgh, then fill ----
  {
    uint32_t* dz = (uint32_t*)(smem + 16384);
    for (int q = tid; q < 7232; q += 256) dz[q] = 0u;
  }
  __syncthreads();
  {
    const float* dsrc = digits + (size_t)g * 7840;
    for (int idx = tid; idx < 7840; idx += 256) {
      int s = idx / 784; int r = idx - s * 784;
      int i = r / 28;    int j = r - i * 28;
      *(_Float16*)(smem + 16384 + (size_t)(s * 904 + i * 32 + j) * 2) = (_Float16)dsrc[idx];
    }
  }
  __syncthreads();

  // ---- per-lane A base addresses for 22 m-tiles ----
  uint32_t addr0[22];
  #pragma unroll
  for (int j2 = 0; j2 < 22; ++j2) {
    int tile = w + 4 * j2;
    int p = tile * 16 + l15;
    int py = p / 37, px = p - py * 37;
    int a0 = py * 64 + px + jo;
    addr0[j2] = ((uint32_t)(a0 & ~1) << 1) + ((uint32_t)(a0 & 1) << 13);
  }

  f32x4 acc[22];
  #pragma unroll
  for (int j2 = 0; j2 < 22; ++j2) acc[j2] = (f32x4){0.f, 0.f, 0.f, 0.f};

  const uint8_t* dghb = smem + 16384;
  for (int i = 0; i < 28; ++i) {
    f16x8 bfrag = *(const f16x8*)(dghb + (size_t)(l15 * 904 + i * 32 + jo) * 2);
    #pragma unroll
    for (int j2 = 0; j2 < 22; ++j2) {
      const uint32_t* ap = (const uint32_t*)(smem + addr0[j2] + i * 128);
      union { uint32_t u[4]; f16x8 v; } A;
      A.u[0] = ap[0]; A.u[1] = ap[1]; A.u[2] = ap[2]; A.u[3] = ap[3];
      acc[j2] = __builtin_amdgcn_mfma_f32_16x16x32_f16(A.v, bfrag, acc[j2], 0, 0, 0);
    }
  }

  // ---- C write: row m = t*1280 + 10g + s (s = l15), col k = p ----
  if (l15 < 10) {
    size_t rb = ((size_t)t * 1280 + 10 * g + l15) * (size_t)CROWB;
    #pragma unroll
    for (int j2 = 0; j2 < 22; ++j2) {
      int p0 = (w + 4 * j2) * 16 + lg * 4;
      #pragma unroll
      for (int r = 0; r < 4; ++r) {
        int p = p0 + r;
        if (p < 1369)
          *(_Float16*)(conv_out + rb + (size_t)p * 2) = (_Float16)acc[j2][r];
      }
    }
  }
}

// ---------------- stage 2+3: MFMA GEMM [64 x 1408] x [1408 x 256] + epi ---
__global__ __launch_bounds__(256) void mlp_mfma(
    const uint8_t* __restrict__ conv_out, const uint8_t* __restrict__ w1t,
    const float* __restrict__ b1, const float* __restrict__ W2,
    const float* __restrict__ b2, const float* __restrict__ wstd,
    float* __restrict__ out)
{
  // A-tile [0,8192): 64 rows x 128B (XOR-swizzled); B-tile [8192,40960): 256 x 128B;
  // qpbuf at 40960: [4 waves][64 rows][2] f32
  __shared__ __align__(16) uint8_t smem[43008];
  const int tid = threadIdx.x;
  const int lane = tid & 63, w = tid >> 6;
  const int l15 = lane & 15, lg = lane >> 4;
  const int m0 = blockIdx.x * 64;

  f32x4 acc[4][4];
  #pragma unroll
  for (int mt = 0; mt < 4; ++mt)
    #pragma unroll
    for (int nj = 0; nj < 4; ++nj) acc[mt][nj] = (f32x4){0.f, 0.f, 0.f, 0.f};

  for (int k0 = 0; k0 < 1408; k0 += 64) {
    __syncthreads();   // previous-tile reads done before overwrite
    // stage A: 64 rows x 128B, swizzled writes
    #pragma unroll
    for (int it = 0; it < 2; ++it) {
      int q = tid + 256 * it; int R = q >> 3, c16 = q & 7;
      uint4 v = *(const uint4*)(conv_out + (size_t)(m0 + R) * CROWB + (size_t)k0 * 2 + c16 * 16);
      *(uint4*)(smem + R * 128 + ((c16 * 16) ^ ((R & 7) << 4))) = v;
    }
    // stage B: 256 rows x 128B
    #pragma unroll
    for (int it = 0; it < 8; ++it) {
      int q = tid + 256 * it; int h = q >> 3, c16 = q & 7;
      uint4 v = *(const uint4*)(w1t + (size_t)h * CROWB + (size_t)k0 * 2 + c16 * 16);
      *(uint4*)(smem + 8192 + h * 128 + ((c16 * 16) ^ ((h & 7) << 4))) = v;
    }
    __syncthreads();
    #pragma unroll
    for (int q = 0; q < 2; ++q) {
      f16x8 bf[4];
      #pragma unroll
      for (int nj = 0; nj < 4; ++nj) {
        int h = (w * 4 + nj) * 16 + l15;
        bf[nj] = *(const f16x8*)(smem + 8192 + h * 128 + ((q * 64 + lg * 16) ^ ((h & 7) << 4)));
      }
      #pragma unroll
      for (int mt = 0; mt < 4; ++mt) {
        int R = mt * 16 + l15;
        union { uint4 u; f16x8 v; } A;
        A.u = *(const uint4*)(smem + R * 128 + ((q * 64 + lg * 16) ^ ((R & 7) << 4)));
        #pragma unroll
        for (int nj = 0; nj < 4; ++nj)
          acc[mt][nj] = __builtin_amdgcn_mfma_f32_16x16x32_f16(A.v, bf[nj], acc[mt][nj], 0, 0, 0);
      }
    }
  }

  // ---- epilogue: tanh + tiny GEMM (H->2), cross-lane then cross-wave ----
  float qp[4][4][2];
  #pragma unroll
  for (int mt = 0; mt < 4; ++mt)
    #pragma unroll
    for (int r = 0; r < 4; ++r) { qp[mt][r][0] = 0.f; qp[mt][r][1] = 0.f; }

  #pragma unroll
  for (int nj = 0; nj < 4; ++nj) {
    int h = (w * 4 + nj) * 16 + l15;
    float bb = b1[h];
    float w20 = W2[2 * h], w21 = W2[2 * h + 1];
    #pragma unroll
    for (int mt = 0; mt < 4; ++mt)
      #pragma unroll
      for (int r = 0; r < 4; ++r) {
        float hid = fast_tanh(acc[mt][nj][r] + bb);
        qp[mt][r][0] = fmaf(hid, w20, qp[mt][r][0]);
        qp[mt][r][1] = fmaf(hid, w21, qp[mt][r][1]);
      }
  }
  #pragma unroll
  for (int off = 1; off <= 8; off <<= 1) {
    #pragma unroll
    for (int mt = 0; mt < 4; ++mt)
      #pragma unroll
      for (int r = 0; r < 4; ++r) {
        qp[mt][r][0] += __shfl_xor(qp[mt][r][0], off);
        qp[mt][r][1] += __shfl_xor(qp[mt][r][1], off);
      }
  }
  float* qb = (float*)(smem + 40960);
  if (l15 == 0) {
    #pragma unroll
    for (int mt = 0; mt < 4; ++mt)
      #pragma unroll
      for (int r = 0; r < 4; ++r) {
        int row = mt * 16 + lg * 4 + r;
        qb[(w * 64 + row) * 2 + 0] = qp[mt][r][0];
        qb[(w * 64 + row) * 2 + 1] = qp[mt][r][1];
      }
  }
  __syncthreads();
  if (tid < 128) {
    int row = tid >> 1, c = tid & 1;
    float sum = qb[row * 2 + c] + qb[(64 + row) * 2 + c] +
                qb[(128 + row) * 2 + c] + qb[(192 + row) * 2 + c];
    float q = fast_tanh(sum + b2[c]);
    int m = m0 + row;
    int tt = m / 1280;
    int o = m - tt * 1280;
    int base = (o * 16 + tt) * 2;
    out[base + c] = q;
    out[NOUT + base + c] = q + wstd[c] * gauss_eps(base + c);
  }
}

extern "C" void kernel_launch(void* const* d_in, const int* in_sizes, int n_in,
                              void* d_out, int out_size, void* d_ws, size_t ws_size,
                              hipStream_t stream) {
  const float* frames = (const float*)d_in[0];
  const float* digits = (const float*)d_in[1];
  const float* W1   = (const float*)d_in[3];
  const float* b1   = (const float*)d_in[4];
  const float* W2   = (const float*)d_in[5];
  const float* b2   = (const float*)d_in[6];
  const float* wstd = (const float*)d_in[7];
  uint8_t* conv_ws = (uint8_t*)d_ws;                          // [20480][2816B] f16
  uint8_t* w1t     = conv_ws + (size_t)20480 * CROWB;         // [256][2816B] f16
  float* out = (float*)d_out;

  prep_w1t<<<dim3(1408), dim3(256), 0, stream>>>(W1, w1t);
  conv_mfma<<<dim3(2048), dim3(256), 0, stream>>>(frames, digits, conv_ws);
  mlp_mfma<<<dim3(320), dim3(256), 0, stream>>>(conv_ws, w1t, b1, W2, b2, wstd, out);
}

// Round 4
// 268.259 us; speedup vs baseline: 3.6752x; 1.0133x over previous
//
#include <hip/hip_runtime.h>
#include <stdint.h>

#define CROWB 2816        // conv_out row bytes (1408 f16, K padded 1369->1408)
#define NOUT 40960
#define DGB 32832         // digit region base in conv smem
#define DGSTR 920         // digit row stride (f16 elems), 1840B = 16B-aligned

typedef _Float16 f16x8 __attribute__((ext_vector_type(8)));
typedef float f32x4 __attribute__((ext_vector_type(4)));

// ---------------- threefry2x32 (key(1) -> (0,1)), partitionable path ------
#define TF_ROT(x, r) (((x) << (r)) | ((x) >> (32 - (r))))
#define TF_ROUND(r) { x0 += x1; x1 = TF_ROT(x1, (r)); x1 ^= x0; }

__device__ __forceinline__ float erfinv_f(float x) {
  float w = -log1pf(-x * x);
  float p;
  if (w < 5.0f) {
    w -= 2.5f;
    p = 2.81022636e-08f;
    p = fmaf(p, w, 3.43273939e-07f);
    p = fmaf(p, w, -3.5233877e-06f);
    p = fmaf(p, w, -4.39150654e-06f);
    p = fmaf(p, w, 0.00021858087f);
    p = fmaf(p, w, -0.00125372503f);
    p = fmaf(p, w, -0.00417768164f);
    p = fmaf(p, w, 0.246640727f);
    p = fmaf(p, w, 1.50140941f);
  } else {
    w = sqrtf(w) - 3.0f;
    p = -0.000200214257f;
    p = fmaf(p, w, 0.000100950558f);
    p = fmaf(p, w, 0.00134934322f);
    p = fmaf(p, w, -0.00367342844f);
    p = fmaf(p, w, 0.00573950773f);
    p = fmaf(p, w, -0.0076224613f);
    p = fmaf(p, w, 0.00943887047f);
    p = fmaf(p, w, 1.00167406f);
    p = fmaf(p, w, 2.83297682f);
  }
  return p * x;
}

__device__ __forceinline__ float gauss_eps(int p) {
  const unsigned ks0 = 0u, ks1 = 1u, ks2 = 0x1BD11BDBu;
  unsigned x0 = 0u + ks0;
  unsigned x1 = (unsigned)p + ks1;
  TF_ROUND(13) TF_ROUND(15) TF_ROUND(26) TF_ROUND(6)
  x0 += ks1; x1 += ks2 + 1u;
  TF_ROUND(17) TF_ROUND(29) TF_ROUND(16) TF_ROUND(24)
  x0 += ks2; x1 += ks0 + 2u;
  TF_ROUND(13) TF_ROUND(15) TF_ROUND(26) TF_ROUND(6)
  x0 += ks0; x1 += ks1 + 3u;
  TF_ROUND(17) TF_ROUND(29) TF_ROUND(16) TF_ROUND(24)
  x0 += ks1; x1 += ks2 + 4u;
  TF_ROUND(13) TF_ROUND(15) TF_ROUND(26) TF_ROUND(6)
  x0 += ks2; x1 += ks0 + 5u;
  unsigned bits = x0 ^ x1;
  unsigned fb = (bits >> 9) | 0x3f800000u;
  float f = __uint_as_float(fb) - 1.0f;
  const float lo = -0.99999994f;
  float u = f * 2.0f + lo;
  u = fmaxf(lo, u);
  return 1.41421356f * erfinv_f(u);
}

__device__ __forceinline__ float fast_tanh(float x) {
  float e = __expf(2.0f * x);
  return 1.0f - 2.0f * __builtin_amdgcn_rcpf(e + 1.0f);
}

__device__ __forceinline__ uint32_t packh2(float lo, float hi) {
  union { _Float16 h[2]; uint32_t u; } c;
  c.h[0] = (_Float16)lo; c.h[1] = (_Float16)hi;
  return c.u;
}

// ---------------- W1 transpose+f16 prep: w1t[h][k] (k padded to 1408) -----
__global__ void prep_w1t(const float* __restrict__ W1, uint8_t* __restrict__ w1t) {
  int k = blockIdx.x;          // 0..1407
  int h = threadIdx.x;         // 0..255
  float v = (k < 1369) ? W1[(size_t)k * 256 + h] : 0.0f;
  *(_Float16*)(w1t + (size_t)h * CROWB + (size_t)k * 2) = (_Float16)v;
}

// ---------------- stage 1: grouped correlation via MFMA -------------------
// Frame LDS layout: byte addr 8*e holds f16 elems {e, e+1, e+2, e+3}.
// Any 8-elem window at elem offset e0 = two aligned b64 reads (8e0, 8e0+32).
__global__ __launch_bounds__(256, 2) void conv_mfma(
    const float* __restrict__ frames, const float* __restrict__ digits,
    uint8_t* __restrict__ conv_out)
{
  // [0, 32832): frame slots (4104 slots x 8B); [32832, 62272): digits f16[16][920]
  __shared__ __align__(16) uint8_t smem[62272];
  const int g = blockIdx.x >> 4, t = blockIdx.x & 15;
  const int tid = threadIdx.x;
  const int lane = tid & 63, w = tid >> 6;
  const int l15 = lane & 15, lg = lane >> 4;
  const int jo = lg * 8;

  // ---- stage frames: thread owns elems [16*tid, 16*tid+16) ----
  {
    const float* fbase = frames + ((size_t)(g * 16 + t)) * 4096;
    float h[20];
    const float4* f4 = (const float4*)(fbase + tid * 16);
    #pragma unroll
    for (int a = 0; a < 4; ++a) {
      float4 v = f4[a];
      h[4*a] = v.x; h[4*a+1] = v.y; h[4*a+2] = v.z; h[4*a+3] = v.w;
    }
    // elems 16..19 come from the next thread (or global/zero at wave edge)
    float t0 = __shfl_down(h[0], 1), t1 = __shfl_down(h[1], 1),
          t2 = __shfl_down(h[2], 1), t3 = __shfl_down(h[3], 1);
    if (lane == 63) {
      int bidx = tid * 16 + 16;
      t0 = (bidx + 0 < 4096) ? fbase[bidx + 0] : 0.0f;
      t1 = (bidx + 1 < 4096) ? fbase[bidx + 1] : 0.0f;
      t2 = (bidx + 2 < 4096) ? fbase[bidx + 2] : 0.0f;
      t3 = (bidx + 3 < 4096) ? fbase[bidx + 3] : 0.0f;
    }
    h[16] = t0; h[17] = t1; h[18] = t2; h[19] = t3;
    // write slot-pairs (e, e+1), e = 16*tid + 2*cc, rotated to spread banks
    #pragma unroll
    for (int c = 0; c < 8; ++c) {
      int cc = (c + tid) & 7;
      int le = 2 * cc;
      uint4 v;
      v.x = packh2(h[le],   h[le+1]);
      v.y = packh2(h[le+2], h[le+3]);
      v.z = packh2(h[le+1], h[le+2]);
      v.w = packh2(h[le+3], h[le+4]);
      *(uint4*)(smem + 128 * tid + 16 * cc) = v;
    }
    // zero pad slots e in [4096, 4104): bytes [32768, 32832)
    if (tid < 16) *(uint32_t*)(smem + 32768 + tid * 4) = 0u;
  }
  // ---- zero digit region ----
  {
    uint32_t* dz = (uint32_t*)(smem + DGB);
    for (int q = tid; q < 7360; q += 256) dz[q] = 0u;
  }
  __syncthreads();
  // ---- fill digits ----
  {
    const float* dsrc = digits + (size_t)g * 7840;
    for (int idx = tid; idx < 7840; idx += 256) {
      int s = idx / 784; int r = idx - s * 784;
      int i = r / 28;    int j = r - i * 28;
      *(_Float16*)(smem + DGB + (size_t)(s * DGSTR + i * 32 + j) * 2) = (_Float16)dsrc[idx];
    }
  }
  __syncthreads();

  // ---- per-lane A base addresses (byte = 8 * elem) for 22 m-tiles ----
  uint32_t abase[22];
  #pragma unroll
  for (int j2 = 0; j2 < 22; ++j2) {
    int tile = w + 4 * j2;
    int p = tile * 16 + l15;
    int py = p / 37, px = p - py * 37;
    abase[j2] = (uint32_t)(py * 64 + px + jo) * 8u;
  }

  f32x4 acc[22];
  #pragma unroll
  for (int j2 = 0; j2 < 22; ++j2) acc[j2] = (f32x4){0.f, 0.f, 0.f, 0.f};

  for (int i = 0; i < 28; ++i) {
    f16x8 bfrag = *(const f16x8*)(smem + DGB + (size_t)(l15 * DGSTR + i * 32 + jo) * 2);
    #pragma unroll
    for (int j2 = 0; j2 < 22; ++j2) {
      const uint8_t* ap = smem + abase[j2] + i * 512;
      union { uint2 u2[2]; f16x8 v; } A;
      A.u2[0] = *(const uint2*)(ap);        // elems e0 .. e0+3
      A.u2[1] = *(const uint2*)(ap + 32);   // elems e0+4 .. e0+7
      acc[j2] = __builtin_amdgcn_mfma_f32_16x16x32_f16(A.v, bfrag, acc[j2], 0, 0, 0);
    }
  }

  // ---- C write: row m = t*1280 + 10g + s (s = l15), col k = p ----
  if (l15 < 10) {
    size_t rb = ((size_t)t * 1280 + 10 * g + l15) * (size_t)CROWB;
    #pragma unroll
    for (int j2 = 0; j2 < 22; ++j2) {
      int p0 = (w + 4 * j2) * 16 + lg * 4;
      #pragma unroll
      for (int r = 0; r < 4; ++r) {
        int p = p0 + r;
        if (p < 1369)
          *(_Float16*)(conv_out + rb + (size_t)p * 2) = (_Float16)acc[j2][r];
      }
    }
  }
}

// ---------------- stage 2+3: MFMA GEMM [64 x 1408] x [1408 x 256] + epi ---
__global__ __launch_bounds__(256) void mlp_mfma(
    const uint8_t* __restrict__ conv_out, const uint8_t* __restrict__ w1t,
    const float* __restrict__ b1, const float* __restrict__ W2,
    const float* __restrict__ b2, const float* __restrict__ wstd,
    float* __restrict__ out)
{
  __shared__ __align__(16) uint8_t smem[43008];
  const int tid = threadIdx.x;
  const int lane = tid & 63, w = tid >> 6;
  const int l15 = lane & 15, lg = lane >> 4;
  const int m0 = blockIdx.x * 64;

  f32x4 acc[4][4];
  #pragma unroll
  for (int mt = 0; mt < 4; ++mt)
    #pragma unroll
    for (int nj = 0; nj < 4; ++nj) acc[mt][nj] = (f32x4){0.f, 0.f, 0.f, 0.f};

  for (int k0 = 0; k0 < 1408; k0 += 64) {
    __syncthreads();
    #pragma unroll
    for (int it = 0; it < 2; ++it) {
      int q = tid + 256 * it; int R = q >> 3, c16 = q & 7;
      uint4 v = *(const uint4*)(conv_out + (size_t)(m0 + R) * CROWB + (size_t)k0 * 2 + c16 * 16);
      *(uint4*)(smem + R * 128 + ((c16 * 16) ^ ((R & 7) << 4))) = v;
    }
    #pragma unroll
    for (int it = 0; it < 8; ++it) {
      int q = tid + 256 * it; int h = q >> 3, c16 = q & 7;
      uint4 v = *(const uint4*)(w1t + (size_t)h * CROWB + (size_t)k0 * 2 + c16 * 16);
      *(uint4*)(smem + 8192 + h * 128 + ((c16 * 16) ^ ((h & 7) << 4))) = v;
    }
    __syncthreads();
    #pragma unroll
    for (int q = 0; q < 2; ++q) {
      f16x8 bf[4];
      #pragma unroll
      for (int nj = 0; nj < 4; ++nj) {
        int h = (w * 4 + nj) * 16 + l15;
        bf[nj] = *(const f16x8*)(smem + 8192 + h * 128 + ((q * 64 + lg * 16) ^ ((h & 7) << 4)));
      }
      #pragma unroll
      for (int mt = 0; mt < 4; ++mt) {
        int R = mt * 16 + l15;
        union { uint4 u; f16x8 v; } A;
        A.u = *(const uint4*)(smem + R * 128 + ((q * 64 + lg * 16) ^ ((R & 7) << 4)));
        #pragma unroll
        for (int nj = 0; nj < 4; ++nj)
          acc[mt][nj] = __builtin_amdgcn_mfma_f32_16x16x32_f16(A.v, bf[nj], acc[mt][nj], 0, 0, 0);
      }
    }
  }

  float qp[4][4][2];
  #pragma unroll
  for (int mt = 0; mt < 4; ++mt)
    #pragma unroll
    for (int r = 0; r < 4; ++r) { qp[mt][r][0] = 0.f; qp[mt][r][1] = 0.f; }

  #pragma unroll
  for (int nj = 0; nj < 4; ++nj) {
    int h = (w * 4 + nj) * 16 + l15;
    float bb = b1[h];
    float w20 = W2[2 * h], w21 = W2[2 * h + 1];
    #pragma unroll
    for (int mt = 0; mt < 4; ++mt)
      #pragma unroll
      for (int r = 0; r < 4; ++r) {
        float hid = fast_tanh(acc[mt][nj][r] + bb);
        qp[mt][r][0] = fmaf(hid, w20, qp[mt][r][0]);
        qp[mt][r][1] = fmaf(hid, w21, qp[mt][r][1]);
      }
  }
  #pragma unroll
  for (int off = 1; off <= 8; off <<= 1) {
    #pragma unroll
    for (int mt = 0; mt < 4; ++mt)
      #pragma unroll
      for (int r = 0; r < 4; ++r) {
        qp[mt][r][0] += __shfl_xor(qp[mt][r][0], off);
        qp[mt][r][1] += __shfl_xor(qp[mt][r][1], off);
      }
  }
  float* qb = (float*)(smem + 40960);
  if (l15 == 0) {
    #pragma unroll
    for (int mt = 0; mt < 4; ++mt)
      #pragma unroll
      for (int r = 0; r < 4; ++r) {
        int row = mt * 16 + lg * 4 + r;
        qb[(w * 64 + row) * 2 + 0] = qp[mt][r][0];
        qb[(w * 64 + row) * 2 + 1] = qp[mt][r][1];
      }
  }
  __syncthreads();
  if (tid < 128) {
    int row = tid >> 1, c = tid & 1;
    float sum = qb[row * 2 + c] + qb[(64 + row) * 2 + c] +
                qb[(128 + row) * 2 + c] + qb[(192 + row) * 2 + c];
    float q = fast_tanh(sum + b2[c]);
    int m = m0 + row;
    int tt = m / 1280;
    int o = m - tt * 1280;
    int base = (o * 16 + tt) * 2;
    out[base + c] = q;
    out[NOUT + base + c] = q + wstd[c] * gauss_eps(base + c);
  }
}

extern "C" void kernel_launch(void* const* d_in, const int* in_sizes, int n_in,
                              void* d_out, int out_size, void* d_ws, size_t ws_size,
                              hipStream_t stream) {
  const float* frames = (const float*)d_in[0];
  const float* digits = (const float*)d_in[1];
  const float* W1   = (const float*)d_in[3];
  const float* b1   = (const float*)d_in[4];
  const float* W2   = (const float*)d_in[5];
  const float* b2   = (const float*)d_in[6];
  const float* wstd = (const float*)d_in[7];
  uint8_t* conv_ws = (uint8_t*)d_ws;                          // [20480][2816B] f16
  uint8_t* w1t     = conv_ws + (size_t)20480 * CROWB;         // [256][2816B] f16
  float* out = (float*)d_out;

  prep_w1t<<<dim3(1408), dim3(256), 0, stream>>>(W1, w1t);
  conv_mfma<<<dim3(2048), dim3(256), 0, stream>>>(frames, digits, conv_ws);
  mlp_mfma<<<dim3(320), dim3(256), 0, stream>>>(conv_ws, w1t, b1, W2, b2, wstd, out);
}